// Round 2
// baseline (1199.895 us; speedup 1.0000x reference)
//
#include <hip/hip_runtime.h>
#include <hip/hip_bf16.h>

// LinearAttention: B=16, C=256, X=Y=64 (n=4096), h=8, d=64, SCALE=0.125
// Pipeline (ws ~74 MB):
//   1) q_fused : q[b,o,n] = softmax_d(W_q x) * SCALE, stored bf16   (o-tile=64=head)
//   2) kv_phi  : per (b,h,n-chunk): k=exp(W_k x), v=W_v x in-block;
//                phi[b,h,d,e] += k·v^T (atomics), lsum[b,h,d] += rowsum(k)
//   3) build_M : M[b,c,h*64+d] = sum_e w_out[c,h*64+e] phi[b,h,d,e] / lsum[b,h,d]
//   4) out_gemm: out[b,c,n] = sum_{o<512} M[b,c,o] q[b,o,n]
// ws layout: q bf16 [16*512*4096] | lsum f32 [16*8*64] | phi f32 [16*8*64*64] | M f32 [16*256*512]

#define BO 64
#define BN 128
#define BK 16

__device__ __forceinline__ float bf2f(unsigned int u16) {
    union { unsigned int i; float f; } w; w.i = u16 << 16; return w.f;
}
__device__ __forceinline__ unsigned short f2bf(float f) {
    union { float f; unsigned int i; } w; w.f = f;
    unsigned int r = w.i + 0x7FFFu + ((w.i >> 16) & 1u);
    return (unsigned short)(r >> 16);
}

// ---------------- kernel 1: q GEMM + softmax over d, store bf16 ----------------
// grid (32 ntiles, 8 heads, 16 b), block 256
__global__ __launch_bounds__(256) void q_fused(
    const float* __restrict__ x,      // [B][256][4096]
    const float* __restrict__ w_qkv,  // [1536][256]
    unsigned short* __restrict__ q)   // [B][512][4096] bf16
{
    const int nb = blockIdx.x * BN;
    const int ob = blockIdx.y * BO;   // head h = blockIdx.y, rows 0..511
    const int b  = blockIdx.z;
    const int tid = threadIdx.x;
    const int tx = tid & 15;
    const int ty = tid >> 4;

    __shared__ float As[BK][BO + 4];
    __shared__ float Bs[BK][BN + 4];
    __shared__ float red[16][BN + 4];
    __shared__ float linv[BN];

    const float* xb = x + (size_t)b * 256 * 4096;

    float acc[4][8];
#pragma unroll
    for (int i = 0; i < 4; i++)
#pragma unroll
        for (int j = 0; j < 8; j++) acc[i][j] = 0.f;

    const int lo = tid >> 2;
    const int lk = (tid & 3) * 4;
    const int lr = tid >> 4;
    const int ln = (tid & 15) * 8;

    for (int k0 = 0; k0 < 256; k0 += BK) {
        float4 a4 = *(const float4*)&w_qkv[(size_t)(ob + lo) * 256 + k0 + lk];
        const float* xr = &xb[(size_t)(k0 + lr) * 4096 + nb + ln];
        float4 b0 = *(const float4*)&xr[0];
        float4 b1 = *(const float4*)&xr[4];
        __syncthreads();
        As[lk + 0][lo] = a4.x; As[lk + 1][lo] = a4.y;
        As[lk + 2][lo] = a4.z; As[lk + 3][lo] = a4.w;
        *(float4*)&Bs[lr][ln] = b0;
        *(float4*)&Bs[lr][ln + 4] = b1;
        __syncthreads();
#pragma unroll
        for (int kk = 0; kk < BK; kk++) {
            float4 av  = *(const float4*)&As[kk][ty * 4];
            float4 bv0 = *(const float4*)&Bs[kk][tx * 8];
            float4 bv1 = *(const float4*)&Bs[kk][tx * 8 + 4];
            float aa[4] = {av.x, av.y, av.z, av.w};
            float bb[8] = {bv0.x, bv0.y, bv0.z, bv0.w, bv1.x, bv1.y, bv1.z, bv1.w};
#pragma unroll
            for (int i = 0; i < 4; i++)
#pragma unroll
                for (int j = 0; j < 8; j++) acc[i][j] += aa[i] * bb[j];
        }
    }
    __syncthreads();

    // softmax over the 64 rows (= d axis), then * SCALE. Values ~N(0,1): exp safe.
#pragma unroll
    for (int i = 0; i < 4; i++)
#pragma unroll
        for (int j = 0; j < 8; j++) acc[i][j] = __expf(acc[i][j]);
#pragma unroll
    for (int j = 0; j < 8; j++)
        red[ty][tx * 8 + j] = acc[0][j] + acc[1][j] + acc[2][j] + acc[3][j];
    __syncthreads();
    if (tid < BN) {
        float s = 0.f;
#pragma unroll
        for (int t = 0; t < 16; t++) s += red[t][tid];
        linv[tid] = 0.125f / s;
    }
    __syncthreads();

    unsigned short* dst = q + ((size_t)b * 512 + ob) * 4096 + nb;
#pragma unroll
    for (int i = 0; i < 4; i++) {
        int row = ty * 4 + i;
        unsigned short tmp[8];
#pragma unroll
        for (int j = 0; j < 8; j++) tmp[j] = f2bf(acc[i][j] * linv[tx * 8 + j]);
        *(uint4*)&dst[(size_t)row * 4096 + tx * 8] = *(uint4*)tmp;
    }
}

// ---------------- kernel 2: fused k,v GEMM + phi accumulation ----------------
// grid (8 nchunks of 512, 8 heads, 16 b), block 256
__global__ __launch_bounds__(256) void kv_phi(
    const float* __restrict__ x, const float* __restrict__ w_qkv,
    float* __restrict__ phi, float* __restrict__ lsum)
{
    const int h = blockIdx.y, b = blockIdx.z;
    const int tid = threadIdx.x;
    const int tx = tid & 15;
    const int ty = tid >> 4;
    const int lo = tid >> 2;
    const int lk = (tid & 3) * 4;
    const int lr = tid >> 4;
    const int ln = (tid & 15) * 8;

    __shared__ float smem[16896];              // 66 KB
    float* Ak = smem;                          // [16][68]
    float* Av = smem + 1088;                   // [16][68]
    float* Bx = smem + 2176;                   // [16][132]
    float* Ks = smem;                          // [64][132] (aliases staging)
    float* Vs = smem + 8448;                   // [64][132]

    const float* xb = x + (size_t)b * 256 * 4096;
    const float* wk = w_qkv + (size_t)(512 + h * 64) * 256;
    const float* wv = w_qkv + (size_t)(1024 + h * 64) * 256;

    float pacc[4][4];
#pragma unroll
    for (int i = 0; i < 4; i++)
#pragma unroll
        for (int j = 0; j < 4; j++) pacc[i][j] = 0.f;

    for (int nt = 0; nt < 4; nt++) {
        const int nb = (blockIdx.x * 4 + nt) * BN;

        float acck[4][8], accv[4][8];
#pragma unroll
        for (int i = 0; i < 4; i++)
#pragma unroll
            for (int j = 0; j < 8; j++) { acck[i][j] = 0.f; accv[i][j] = 0.f; }

        for (int k0 = 0; k0 < 256; k0 += BK) {
            float4 a1 = *(const float4*)&wk[(size_t)lo * 256 + k0 + lk];
            float4 a2 = *(const float4*)&wv[(size_t)lo * 256 + k0 + lk];
            const float* xr = &xb[(size_t)(k0 + lr) * 4096 + nb + ln];
            float4 b0 = *(const float4*)&xr[0];
            float4 b1 = *(const float4*)&xr[4];
            __syncthreads();   // prior readers (GEMM or phi loop) done
            Ak[(lk + 0) * 68 + lo] = a1.x; Ak[(lk + 1) * 68 + lo] = a1.y;
            Ak[(lk + 2) * 68 + lo] = a1.z; Ak[(lk + 3) * 68 + lo] = a1.w;
            Av[(lk + 0) * 68 + lo] = a2.x; Av[(lk + 1) * 68 + lo] = a2.y;
            Av[(lk + 2) * 68 + lo] = a2.z; Av[(lk + 3) * 68 + lo] = a2.w;
            *(float4*)&Bx[lr * 132 + ln] = b0;
            *(float4*)&Bx[lr * 132 + ln + 4] = b1;
            __syncthreads();
#pragma unroll
            for (int kk = 0; kk < BK; kk++) {
                float4 ka4 = *(const float4*)&Ak[kk * 68 + ty * 4];
                float4 va4 = *(const float4*)&Av[kk * 68 + ty * 4];
                float4 bv0 = *(const float4*)&Bx[kk * 132 + tx * 8];
                float4 bv1 = *(const float4*)&Bx[kk * 132 + tx * 8 + 4];
                float ka[4] = {ka4.x, ka4.y, ka4.z, ka4.w};
                float va[4] = {va4.x, va4.y, va4.z, va4.w};
                float bb[8] = {bv0.x, bv0.y, bv0.z, bv0.w, bv1.x, bv1.y, bv1.z, bv1.w};
#pragma unroll
                for (int i = 0; i < 4; i++)
#pragma unroll
                    for (int j = 0; j < 8; j++) {
                        acck[i][j] += ka[i] * bb[j];
                        accv[i][j] += va[i] * bb[j];
                    }
            }
        }
        __syncthreads();   // all GEMM reads of staging done

        // exp(k), row-sums -> lsum
#pragma unroll
        for (int i = 0; i < 4; i++) {
#pragma unroll
            for (int j = 0; j < 8; j++) acck[i][j] = __expf(acck[i][j]);
            float s = acck[i][0] + acck[i][1] + acck[i][2] + acck[i][3]
                    + acck[i][4] + acck[i][5] + acck[i][6] + acck[i][7];
            s += __shfl_xor(s, 8);
            s += __shfl_xor(s, 4);
            s += __shfl_xor(s, 2);
            s += __shfl_xor(s, 1);
            if (tx == 0)
                atomicAdd(&lsum[((size_t)b * 8 + h) * 64 + ty * 4 + i], s);
        }

        // stage expk, v into LDS [row d/e][col n]
#pragma unroll
        for (int i = 0; i < 4; i++) {
            int row = ty * 4 + i;
            *(float4*)&Ks[row * 132 + tx * 8] =
                make_float4(acck[i][0], acck[i][1], acck[i][2], acck[i][3]);
            *(float4*)&Ks[row * 132 + tx * 8 + 4] =
                make_float4(acck[i][4], acck[i][5], acck[i][6], acck[i][7]);
            *(float4*)&Vs[row * 132 + tx * 8] =
                make_float4(accv[i][0], accv[i][1], accv[i][2], accv[i][3]);
            *(float4*)&Vs[row * 132 + tx * 8 + 4] =
                make_float4(accv[i][4], accv[i][5], accv[i][6], accv[i][7]);
        }
        __syncthreads();

        // phi partial: pacc[d][e] += sum_n Ks[d][n]*Vs[e][n]
#pragma unroll 8
        for (int n4 = 0; n4 < 32; n4++) {
            float4 kv[4], vv[4];
#pragma unroll
            for (int i = 0; i < 4; i++)
                kv[i] = *(const float4*)&Ks[(ty * 4 + i) * 132 + n4 * 4];
#pragma unroll
            for (int j = 0; j < 4; j++)
                vv[j] = *(const float4*)&Vs[(tx * 4 + j) * 132 + n4 * 4];
#pragma unroll
            for (int i = 0; i < 4; i++)
#pragma unroll
                for (int j = 0; j < 4; j++)
                    pacc[i][j] += kv[i].x * vv[j].x + kv[i].y * vv[j].y
                                + kv[i].z * vv[j].z + kv[i].w * vv[j].w;
        }
    }

    float* pp = phi + ((size_t)b * 8 + h) * 64 * 64;
#pragma unroll
    for (int i = 0; i < 4; i++)
#pragma unroll
        for (int j = 0; j < 4; j++)
            atomicAdd(&pp[(ty * 4 + i) * 64 + tx * 4 + j], pacc[i][j]);
}

// ---------------- kernel 3: M[b,c,h*64+d] = sum_e w_out*phi/l ----------------
// grid (8 h, 16 b), block 256 (thread = c)
__global__ __launch_bounds__(256) void build_M(
    const float* __restrict__ phi, const float* __restrict__ lsum,
    const float* __restrict__ w_out, float* __restrict__ M)
{
    const int h = blockIdx.x, b = blockIdx.y;
    __shared__ float pT[64][68];  // [e][d]
    const float* pp = phi + ((size_t)b * 8 + h) * 64 * 64;  // [d][e]
    const int tid = threadIdx.x;
    const int row = tid >> 2, ls = tid & 3;
#pragma unroll
    for (int u = 0; u < 4; u++) {
        int e0 = (ls + u * 4) * 4;
        float4 v = *(const float4*)&pp[row * 64 + e0];
        pT[e0 + 0][row] = v.x; pT[e0 + 1][row] = v.y;
        pT[e0 + 2][row] = v.z; pT[e0 + 3][row] = v.w;
    }
    __syncthreads();
    const int c = tid;
    float acc[64];
#pragma unroll
    for (int d = 0; d < 64; d++) acc[d] = 0.f;
    for (int e4 = 0; e4 < 16; e4++) {
        float4 wv = *(const float4*)&w_out[(size_t)c * 512 + h * 64 + e4 * 4];
        float wq[4] = {wv.x, wv.y, wv.z, wv.w};
#pragma unroll
        for (int qq = 0; qq < 4; qq++) {
            int e = e4 * 4 + qq;
#pragma unroll
            for (int d4 = 0; d4 < 16; d4++) {
                float4 p = *(const float4*)&pT[e][d4 * 4];
                acc[d4 * 4 + 0] += wq[qq] * p.x;
                acc[d4 * 4 + 1] += wq[qq] * p.y;
                acc[d4 * 4 + 2] += wq[qq] * p.z;
                acc[d4 * 4 + 3] += wq[qq] * p.w;
            }
        }
    }
    const float* lrow = lsum + ((size_t)b * 8 + h) * 64;
    float* Mrow = M + ((size_t)b * 256 + c) * 512 + h * 64;
#pragma unroll
    for (int d4 = 0; d4 < 16; d4++) {
        float4 o;
        o.x = acc[d4 * 4 + 0] / lrow[d4 * 4 + 0];
        o.y = acc[d4 * 4 + 1] / lrow[d4 * 4 + 1];
        o.z = acc[d4 * 4 + 2] / lrow[d4 * 4 + 2];
        o.w = acc[d4 * 4 + 3] / lrow[d4 * 4 + 3];
        *(float4*)&Mrow[d4 * 4] = o;
    }
}

// ---------------- kernel 4: out[b,c,n] = sum_{o<512} M[b,c,o] q[b,o,n] ----------------
// grid (32 ntiles, 4 ctiles, 16 b), block 256; q is bf16
__global__ __launch_bounds__(256) void out_gemm(
    const float* __restrict__ M, const unsigned short* __restrict__ q,
    float* __restrict__ out)
{
    const int nb = blockIdx.x * BN;
    const int cb = blockIdx.y * BO;
    const int b  = blockIdx.z;
    const int tid = threadIdx.x;
    const int tx = tid & 15;
    const int ty = tid >> 4;

    __shared__ float As[BK][BO + 4];
    __shared__ float Bs[BK][BN + 4];

    const float* A = M + (size_t)b * 256 * 512;
    const unsigned short* Bq = q + (size_t)b * 512 * 4096;

    float acc[4][8];
#pragma unroll
    for (int i = 0; i < 4; i++)
#pragma unroll
        for (int j = 0; j < 8; j++) acc[i][j] = 0.f;

    const int lo = tid >> 2;
    const int lk = (tid & 3) * 4;
    const int lr = tid >> 4;
    const int ln = (tid & 15) * 8;

    for (int k0 = 0; k0 < 512; k0 += BK) {
        float4 a4 = *(const float4*)&A[(size_t)(cb + lo) * 512 + k0 + lk];
        uint4 u = *(const uint4*)&Bq[(size_t)(k0 + lr) * 4096 + nb + ln];
        __syncthreads();
        As[lk + 0][lo] = a4.x; As[lk + 1][lo] = a4.y;
        As[lk + 2][lo] = a4.z; As[lk + 3][lo] = a4.w;
        Bs[lr][ln + 0] = bf2f(u.x & 0xffffu); Bs[lr][ln + 1] = bf2f(u.x >> 16);
        Bs[lr][ln + 2] = bf2f(u.y & 0xffffu); Bs[lr][ln + 3] = bf2f(u.y >> 16);
        Bs[lr][ln + 4] = bf2f(u.z & 0xffffu); Bs[lr][ln + 5] = bf2f(u.z >> 16);
        Bs[lr][ln + 6] = bf2f(u.w & 0xffffu); Bs[lr][ln + 7] = bf2f(u.w >> 16);
        __syncthreads();
#pragma unroll
        for (int kk = 0; kk < BK; kk++) {
            float4 av  = *(const float4*)&As[kk][ty * 4];
            float4 bv0 = *(const float4*)&Bs[kk][tx * 8];
            float4 bv1 = *(const float4*)&Bs[kk][tx * 8 + 4];
            float aa[4] = {av.x, av.y, av.z, av.w};
            float bb[8] = {bv0.x, bv0.y, bv0.z, bv0.w, bv1.x, bv1.y, bv1.z, bv1.w};
#pragma unroll
            for (int i = 0; i < 4; i++)
#pragma unroll
                for (int j = 0; j < 8; j++) acc[i][j] += aa[i] * bb[j];
        }
    }

    float* dst = out + ((size_t)b * 256 + cb) * 4096 + nb;
#pragma unroll
    for (int i = 0; i < 4; i++) {
        int row = ty * 4 + i;
        *(float4*)&dst[(size_t)row * 4096 + tx * 8] =
            make_float4(acc[i][0], acc[i][1], acc[i][2], acc[i][3]);
        *(float4*)&dst[(size_t)row * 4096 + tx * 8 + 4] =
            make_float4(acc[i][4], acc[i][5], acc[i][6], acc[i][7]);
    }
}

extern "C" void kernel_launch(void* const* d_in, const int* in_sizes, int n_in,
                              void* d_out, int out_size, void* d_ws, size_t ws_size,
                              hipStream_t stream) {
    const float* x     = (const float*)d_in[0];
    const float* w_qkv = (const float*)d_in[1];
    const float* w_out = (const float*)d_in[2];
    float* out = (float*)d_out;

    unsigned short* qws = (unsigned short*)d_ws;          // 33,554,432 bf16 = 67,108,864 B
    float* lsum = (float*)((char*)d_ws + 67108864);       // 8,192 f32
    float* phi  = lsum + 8192;                            // 524,288 f32
    float* M    = phi + 524288;                           // 2,097,152 f32
    // total ws use: 77,627,392 bytes

    hipMemsetAsync(lsum, 0, (8192 + 524288) * sizeof(float), stream);

    q_fused<<<dim3(32, 8, 16), 256, 0, stream>>>(x, w_qkv, qws);
    kv_phi<<<dim3(8, 8, 16), 256, 0, stream>>>(x, w_qkv, phi, lsum);
    build_M<<<dim3(8, 16), 256, 0, stream>>>(phi, lsum, w_out, M);
    out_gemm<<<dim3(32, 4, 16), 256, 0, stream>>>(M, qws, out);
}

// Round 4
// 382.014 us; speedup vs baseline: 3.1410x; 3.1410x over previous
//
#include <hip/hip_runtime.h>
#include <hip/hip_bf16.h>

// LinearAttention MI355X: B=16, C=256, n=4096, h=8, d=64, SCALE=0.125
// bf16 MFMA pipeline (ws ~74 MB):
//   K0 cvt_w    : wt = bf16(w_qkv)                                   [1536][256]
//   K1 q_mfma   : q = softmax_d(Wq x)*SCALE -> qT[b][n][o] bf16 (o-contig)
//   K2 kv_phi   : per (b,h,512n): k/v GEMM (MFMA) -> exp -> LDS -> phi MFMA
//                 phi[b,h,d,e] atomics, lsum[b,h,d] atomics
//   K3 build_M  : Mbf[b,c,h*64+d] = bf16( sum_e w_out[c,h*64+e] phi/lsum )
//   K4 out_mfma : out[b,c,n] = sum_o Mbf[c,o] qT[n,o]   (both K-contig)
// R3 fix: q_mfma qT epilogue previously wrote only 16 of 32 shorts per
// (n,half) -> half of qT was poison. Now writes all 4 uint4s.

typedef __attribute__((ext_vector_type(8))) short bf16x8;
typedef __attribute__((ext_vector_type(4))) float f32x4;

__device__ __forceinline__ unsigned short f2bf(float f) {
    union { float f; unsigned int i; } w; w.f = f;
    unsigned int r = w.i + 0x7FFFu + ((w.i >> 16) & 1u);
    return (unsigned short)(r >> 16);
}

// ---------------- K0: w_qkv fp32 -> bf16 ----------------
__global__ __launch_bounds__(256) void cvt_w(
    const float* __restrict__ wqkv, unsigned short* __restrict__ wt)
{
    int idx = (blockIdx.x * 256 + threadIdx.x) * 8;   // 393216 total, grid 192
    float4 f0 = *(const float4*)&wqkv[idx];
    float4 f1 = *(const float4*)&wqkv[idx + 4];
    unsigned short t[8] = {f2bf(f0.x), f2bf(f0.y), f2bf(f0.z), f2bf(f0.w),
                           f2bf(f1.x), f2bf(f1.y), f2bf(f1.z), f2bf(f1.w)};
    *(uint4*)&wt[idx] = *(uint4*)t;
}

// ---------------- K1: q GEMM (MFMA) + softmax over d -> qT bf16 ----------------
// grid (32 ntiles, 8 h, 16 b), block 256 (4 waves)
__global__ __launch_bounds__(256) void q_mfma(
    const float* __restrict__ x, const unsigned short* __restrict__ wt,
    unsigned short* __restrict__ qT)
{
    const int nb = blockIdx.x * 128;
    const int h  = blockIdx.y;
    const int b  = blockIdx.z;
    const int tid  = threadIdx.x;
    const int lane = tid & 63;
    const int w    = tid >> 6;
    const int quad = lane >> 4;
    const int l15  = lane & 15;

    __shared__ unsigned short Ws[64 * 40];    // [o][32c], pad 40 (80B rows)
    __shared__ unsigned short Xs[128 * 40];   // [n][32c] transposed bf16
    __shared__ float red[5 * 128];            // 4 wave partials + linv
    __shared__ unsigned short Qs[128 * 72];   // repack [n][64o], pad 72

    f32x4 acc[8];
#pragma unroll
    for (int i = 0; i < 8; i++) acc[i] = (f32x4)(0.f);

    const int wrow = tid >> 2;                // W stage: row 0..63
    const int wch  = (tid & 3) * 8;           // c-chunk of 8
    const int cp   = tid >> 4;                // x stage: c-pair 0..15
    const int xn   = tid & 15;                // n base

    const unsigned short* wq = wt + (size_t)(h * 64) * 256;
    const float* xb = x + ((size_t)b * 256) * 4096 + nb;

    for (int ks = 0; ks < 8; ks++) {
        const int c0 = ks * 32;
        uint4 wv4 = *(const uint4*)&wq[(size_t)wrow * 256 + c0 + wch];
        float xv[16];
        const float* xr0 = xb + (size_t)(c0 + 2 * cp) * 4096;
        const float* xr1 = xr0 + 4096;
#pragma unroll
        for (int i = 0; i < 8; i++) {
            xv[i]     = xr0[xn + 16 * i];
            xv[8 + i] = xr1[xn + 16 * i];
        }
        __syncthreads();
        *(uint4*)&Ws[wrow * 40 + wch] = wv4;
#pragma unroll
        for (int i = 0; i < 8; i++) {
            unsigned int p = (unsigned int)f2bf(xv[i]) |
                             ((unsigned int)f2bf(xv[8 + i]) << 16);
            *(unsigned int*)&Xs[(xn + 16 * i) * 40 + 2 * cp] = p;
        }
        __syncthreads();
        bf16x8 af = *(bf16x8*)&Ws[(w * 16 + l15) * 40 + quad * 8];
#pragma unroll
        for (int nt = 0; nt < 8; nt++) {
            bf16x8 bf = *(bf16x8*)&Xs[(nt * 16 + l15) * 40 + quad * 8];
            acc[nt] = __builtin_amdgcn_mfma_f32_16x16x32_bf16(af, bf, acc[nt], 0, 0, 0);
        }
    }
    __syncthreads();

    // exp + softmax over d (64 rows across 4 waves)
#pragma unroll
    for (int nt = 0; nt < 8; nt++) {
#pragma unroll
        for (int r = 0; r < 4; r++) acc[nt][r] = __expf(acc[nt][r]);
        float s = acc[nt][0] + acc[nt][1] + acc[nt][2] + acc[nt][3];
        s += __shfl_xor(s, 16);
        s += __shfl_xor(s, 32);
        if (quad == 0) red[w * 128 + nt * 16 + l15] = s;
    }
    __syncthreads();
    if (tid < 128) {
        float t = red[tid] + red[128 + tid] + red[256 + tid] + red[384 + tid];
        red[512 + tid] = 0.125f / t;
    }
    __syncthreads();
#pragma unroll
    for (int nt = 0; nt < 8; nt++) {
        float li = red[512 + nt * 16 + l15];
        uint2 pp;
        pp.x = (unsigned int)f2bf(acc[nt][0] * li) |
               ((unsigned int)f2bf(acc[nt][1] * li) << 16);
        pp.y = (unsigned int)f2bf(acc[nt][2] * li) |
               ((unsigned int)f2bf(acc[nt][3] * li) << 16);
        *(uint2*)&Qs[(nt * 16 + l15) * 72 + w * 16 + quad * 4] = pp;
    }
    __syncthreads();
    {
        const int n = tid >> 1, half = tid & 1;
        unsigned short* dst = qT + ((size_t)(b * 4096 + nb + n)) * 512 + h * 64 + half * 32;
#pragma unroll
        for (int u = 0; u < 4; u++)
            *(uint4*)&dst[u * 8] = *(uint4*)&Qs[n * 72 + half * 32 + u * 8];
    }
}

// ---------------- K2: fused k/v GEMM + phi, all MFMA ----------------
// grid (8 chunks of 512n, 8 h, 16 b), block 256
__global__ __launch_bounds__(256) void kv_phi_mfma(
    const float* __restrict__ x, const unsigned short* __restrict__ wt,
    float* __restrict__ phi, float* __restrict__ lsum)
{
    const int ch = blockIdx.x;
    const int h  = blockIdx.y;
    const int b  = blockIdx.z;
    const int tid  = threadIdx.x;
    const int lane = tid & 63;
    const int w    = tid >> 6;
    const int quad = lane >> 4;
    const int l15  = lane & 15;

    __shared__ unsigned short Wks[64 * 40];   // 5 KB
    __shared__ unsigned short Wvs[64 * 40];   // 5 KB
    __shared__ unsigned short Xs[128 * 40];   // 10 KB
    __shared__ unsigned short Es[64 * 128];   // 16 KB  expk, XOR-swizzled chunks
    __shared__ unsigned short Vs[64 * 128];   // 16 KB  v

    f32x4 pacc[4];
#pragma unroll
    for (int i = 0; i < 4; i++) pacc[i] = (f32x4)(0.f);
    float lacc[4] = {0.f, 0.f, 0.f, 0.f};

    const int wrow = tid >> 2;
    const int wch  = (tid & 3) * 8;
    const int cp   = tid >> 4;
    const int xn   = tid & 15;

    const unsigned short* wk  = wt + (size_t)(512 + h * 64) * 256;
    const unsigned short* wv_ = wt + (size_t)(1024 + h * 64) * 256;

    for (int st = 0; st < 4; st++) {
        const int nb = ch * 512 + st * 128;
        const float* xb = x + ((size_t)b * 256) * 4096 + nb;

        f32x4 acck[8], accv[8];
#pragma unroll
        for (int i = 0; i < 8; i++) { acck[i] = (f32x4)(0.f); accv[i] = (f32x4)(0.f); }

        for (int ks = 0; ks < 8; ks++) {
            const int c0 = ks * 32;
            uint4 wk4 = *(const uint4*)&wk[(size_t)wrow * 256 + c0 + wch];
            uint4 wv4 = *(const uint4*)&wv_[(size_t)wrow * 256 + c0 + wch];
            float xv[16];
            const float* xr0 = xb + (size_t)(c0 + 2 * cp) * 4096;
            const float* xr1 = xr0 + 4096;
#pragma unroll
            for (int i = 0; i < 8; i++) {
                xv[i]     = xr0[xn + 16 * i];
                xv[8 + i] = xr1[xn + 16 * i];
            }
            __syncthreads();   // also protects Es/Vs of previous subtile
            *(uint4*)&Wks[wrow * 40 + wch] = wk4;
            *(uint4*)&Wvs[wrow * 40 + wch] = wv4;
#pragma unroll
            for (int i = 0; i < 8; i++) {
                unsigned int p = (unsigned int)f2bf(xv[i]) |
                                 ((unsigned int)f2bf(xv[8 + i]) << 16);
                *(unsigned int*)&Xs[(xn + 16 * i) * 40 + 2 * cp] = p;
            }
            __syncthreads();
            bf16x8 ak = *(bf16x8*)&Wks[(w * 16 + l15) * 40 + quad * 8];
            bf16x8 av = *(bf16x8*)&Wvs[(w * 16 + l15) * 40 + quad * 8];
#pragma unroll
            for (int nt = 0; nt < 8; nt++) {
                bf16x8 bf = *(bf16x8*)&Xs[(nt * 16 + l15) * 40 + quad * 8];
                acck[nt] = __builtin_amdgcn_mfma_f32_16x16x32_bf16(ak, bf, acck[nt], 0, 0, 0);
                accv[nt] = __builtin_amdgcn_mfma_f32_16x16x32_bf16(av, bf, accv[nt], 0, 0, 0);
            }
        }
        __syncthreads();   // GEMM reads done; now write Es/Vs

        // exp(k), lsum partials, deposit to swizzled LDS tiles
#pragma unroll
        for (int r = 0; r < 4; r++) {
            const int dl = quad * 4 + r;                       // d & 15
            const int dbase = (w * 16 + dl) * 256 + (l15 & 7) * 2;  // byte offset
#pragma unroll
            for (int nt = 0; nt < 8; nt++) {
                const int pos = (2 * nt + (l15 >> 3)) ^ dl;
                float ek = __expf(acck[nt][r]);
                lacc[r] += ek;
                *(unsigned short*)((char*)Es + dbase + pos * 16) = f2bf(ek);
                *(unsigned short*)((char*)Vs + dbase + pos * 16) = f2bf(accv[nt][r]);
            }
        }
        __syncthreads();

        // phi MFMA: phi[d][e] += sum_n expk[d][n] v[e][n], K=128 in 4 steps
#pragma unroll
        for (int k2 = 0; k2 < 4; k2++) {
            bf16x8 ae = *(bf16x8*)((char*)Es + (w * 16 + l15) * 256 +
                                   (((k2 * 4 + quad) ^ l15) * 16));
#pragma unroll
            for (int et = 0; et < 4; et++) {
                bf16x8 bv = *(bf16x8*)((char*)Vs + (et * 16 + l15) * 256 +
                                       (((k2 * 4 + quad) ^ l15) * 16));
                pacc[et] = __builtin_amdgcn_mfma_f32_16x16x32_bf16(ae, bv, pacc[et], 0, 0, 0);
            }
        }
        // next subtile's first __syncthreads protects Es/Vs rewrite
    }

    // lsum: reduce cols (l15) then atomic per d-row
#pragma unroll
    for (int r = 0; r < 4; r++) {
        float s = lacc[r];
        s += __shfl_xor(s, 1); s += __shfl_xor(s, 2);
        s += __shfl_xor(s, 4); s += __shfl_xor(s, 8);
        if (l15 == 0)
            atomicAdd(&lsum[((size_t)b * 8 + h) * 64 + w * 16 + quad * 4 + r], s);
    }
    float* pp = phi + ((size_t)b * 8 + h) * 4096;
#pragma unroll
    for (int et = 0; et < 4; et++)
#pragma unroll
        for (int r = 0; r < 4; r++)
            atomicAdd(&pp[(w * 16 + quad * 4 + r) * 64 + et * 16 + l15], pacc[et][r]);
}

// ---------------- K3: M = w_out · (phi/l), bf16 out ----------------
// grid (8 h, 16 b), block 256 (thread = c)
__global__ __launch_bounds__(256) void build_M(
    const float* __restrict__ phi, const float* __restrict__ lsum,
    const float* __restrict__ w_out, unsigned short* __restrict__ Mbf)
{
    const int h = blockIdx.x, b = blockIdx.y;
    __shared__ float pT[64][68];  // [e][d]
    const float* pp = phi + ((size_t)b * 8 + h) * 4096;  // [d][e]
    const int tid = threadIdx.x;
    const int row = tid >> 2, ls = tid & 3;
#pragma unroll
    for (int u = 0; u < 4; u++) {
        int e0 = (ls + u * 4) * 4;
        float4 v = *(const float4*)&pp[row * 64 + e0];
        pT[e0 + 0][row] = v.x; pT[e0 + 1][row] = v.y;
        pT[e0 + 2][row] = v.z; pT[e0 + 3][row] = v.w;
    }
    __syncthreads();
    const int c = tid;
    float acc[64];
#pragma unroll
    for (int d = 0; d < 64; d++) acc[d] = 0.f;
    for (int e4 = 0; e4 < 16; e4++) {
        float4 wv = *(const float4*)&w_out[(size_t)c * 512 + h * 64 + e4 * 4];
        float wq[4] = {wv.x, wv.y, wv.z, wv.w};
#pragma unroll
        for (int qq = 0; qq < 4; qq++) {
            int e = e4 * 4 + qq;
#pragma unroll
            for (int d4 = 0; d4 < 16; d4++) {
                float4 p = *(const float4*)&pT[e][d4 * 4];
                acc[d4 * 4 + 0] += wq[qq] * p.x;
                acc[d4 * 4 + 1] += wq[qq] * p.y;
                acc[d4 * 4 + 2] += wq[qq] * p.z;
                acc[d4 * 4 + 3] += wq[qq] * p.w;
            }
        }
    }
    const float* lrow = lsum + ((size_t)b * 8 + h) * 64;
    unsigned short tmp[64];
#pragma unroll
    for (int d = 0; d < 64; d++) tmp[d] = f2bf(acc[d] / lrow[d]);
    unsigned short* Mrow = Mbf + ((size_t)b * 256 + c) * 512 + h * 64;
#pragma unroll
    for (int u = 0; u < 8; u++)
        *(uint4*)&Mrow[u * 8] = *(uint4*)&tmp[u * 8];
}

// ---------------- K4: out = Mbf · qT^T (both K=o contiguous) ----------------
// grid (32 ntiles, 4 ctiles, 16 b), block 256
__global__ __launch_bounds__(256) void out_mfma(
    const unsigned short* __restrict__ Mbf, const unsigned short* __restrict__ qT,
    float* __restrict__ out)
{
    const int nb = blockIdx.x * 128;
    const int cb = blockIdx.y * 64;
    const int b  = blockIdx.z;
    const int tid  = threadIdx.x;
    const int lane = tid & 63;
    const int w    = tid >> 6;
    const int quad = lane >> 4;
    const int l15  = lane & 15;

    __shared__ unsigned short As[64 * 40];    // Mbf tile [c][32o]
    __shared__ unsigned short Bs[128 * 40];   // qT tile [n][32o]

    f32x4 acc[8];
#pragma unroll
    for (int i = 0; i < 8; i++) acc[i] = (f32x4)(0.f);

    const unsigned short* Ab = Mbf + ((size_t)b * 256 + cb) * 512;
    const unsigned short* Bb = qT + ((size_t)b * 4096 + nb) * 512;
    const int arow = tid >> 2, ach = (tid & 3) * 8;

    for (int ks = 0; ks < 16; ks++) {
        const int o0 = ks * 32;
        uint4 a4 = *(const uint4*)&Ab[(size_t)arow * 512 + o0 + ach];
        uint4 b4 = *(const uint4*)&Bb[(size_t)arow * 512 + o0 + ach];
        uint4 b5 = *(const uint4*)&Bb[(size_t)(64 + arow) * 512 + o0 + ach];
        __syncthreads();
        *(uint4*)&As[arow * 40 + ach] = a4;
        *(uint4*)&Bs[arow * 40 + ach] = b4;
        *(uint4*)&Bs[(64 + arow) * 40 + ach] = b5;
        __syncthreads();
        bf16x8 af = *(bf16x8*)&As[(w * 16 + l15) * 40 + quad * 8];
#pragma unroll
        for (int nt = 0; nt < 8; nt++) {
            bf16x8 bf = *(bf16x8*)&Bs[(nt * 16 + l15) * 40 + quad * 8];
            acc[nt] = __builtin_amdgcn_mfma_f32_16x16x32_bf16(af, bf, acc[nt], 0, 0, 0);
        }
    }
    float* ob = out + ((size_t)b * 256 + cb) * 4096 + nb;
#pragma unroll
    for (int nt = 0; nt < 8; nt++)
#pragma unroll
        for (int r = 0; r < 4; r++)
            ob[(size_t)(w * 16 + quad * 4 + r) * 4096 + nt * 16 + l15] = acc[nt][r];
}

extern "C" void kernel_launch(void* const* d_in, const int* in_sizes, int n_in,
                              void* d_out, int out_size, void* d_ws, size_t ws_size,
                              hipStream_t stream) {
    const float* x     = (const float*)d_in[0];
    const float* w_qkv = (const float*)d_in[1];
    const float* w_out = (const float*)d_in[2];
    float* out = (float*)d_out;

    unsigned short* qT  = (unsigned short*)d_ws;                       // 67,108,864 B
    unsigned short* wt  = (unsigned short*)((char*)d_ws + 67108864);   //    786,432 B
    float* lsum = (float*)((char*)d_ws + 67108864 + 786432);           //     32,768 B
    float* phi  = lsum + 8192;                                         //  2,097,152 B
    unsigned short* Mbf = (unsigned short*)((char*)phi + 524288 * 4);  //  4,194,304 B
    // total ws: ~74.2 MB (proven-safe budget)

    hipMemsetAsync(lsum, 0, (8192 + 524288) * sizeof(float), stream);

    cvt_w<<<192, 256, 0, stream>>>(w_qkv, wt);
    q_mfma<<<dim3(32, 8, 16), 256, 0, stream>>>(x, wt, qT);
    kv_phi_mfma<<<dim3(8, 8, 16), 256, 0, stream>>>(x, wt, phi, lsum);
    build_M<<<dim3(8, 16), 256, 0, stream>>>(phi, lsum, w_out, Mbf);
    out_mfma<<<dim3(32, 4, 16), 256, 0, stream>>>(Mbf, qT, out);
}